// Round 9
// baseline (4486.292 us; speedup 1.0000x reference)
//
#include <hip/hip_runtime.h>
#include <math.h>

#define BB 8
#define SS 2048
#define D_IN 1024
#define D_OUTC 1024
#define LATC 256
#define NSTATE 32
#define DINNER 2048
#define DCONV 4
#define DTRANK 64

__device__ __forceinline__ float silu_f(float v) { return v * (1.f / (1.f + __expf(-v))); }
__device__ __forceinline__ float softplus_f(float v) {
    return fmaxf(v, 0.f) + log1pf(__expf(-fabsf(v)));
}

// ---------------------------------------------------------------------------
// Generic tiled GEMM: C[M,N] = act(A[M,K] @ B[K,N] + bias) (optionally +=)
// transA -> A stored [K, M] with leading dim lda. All fp32.
// 64x64 tile, 16x16 threads, 4x4 per thread, BK=16.
// ---------------------------------------------------------------------------
__global__ __launch_bounds__(256) void gemm_kernel(
    const float* __restrict__ A, int lda, long strideA,
    const float* __restrict__ B, int ldb, long strideB,
    const float* __restrict__ bias,
    float* __restrict__ C, int ldc, long strideC,
    int M, int N, int K, int transA, int act, int accum)
{
    __shared__ float As[16][65];
    __shared__ float Bs[16][64];

    const int bz = blockIdx.z;
    const float* Ab = A + (size_t)bz * strideA;
    const float* Bb = B + (size_t)bz * strideB;
    float* Cb = C + (size_t)bz * strideC;

    const int tx = threadIdx.x;  // 0..15
    const int ty = threadIdx.y;  // 0..15
    const int tid = ty * 16 + tx;
    const int m0 = blockIdx.y * 64;
    const int n0 = blockIdx.x * 64;

    float acc[4][4];
#pragma unroll
    for (int i = 0; i < 4; i++)
#pragma unroll
        for (int j = 0; j < 4; j++) acc[i][j] = 0.f;

    for (int k0 = 0; k0 < K; k0 += 16) {
        if (!transA) {
            int row = tid >> 2;           // 0..63
            int kc = (tid & 3) * 4;       // 0,4,8,12
            int gm = m0 + row;
#pragma unroll
            for (int j = 0; j < 4; j++) {
                int gk = k0 + kc + j;
                As[kc + j][row] = (gm < M && gk < K) ? Ab[(size_t)gm * lda + gk] : 0.f;
            }
        } else {
            int krow = tid >> 4;          // 0..15
            int mc = (tid & 15) * 4;
            int gk = k0 + krow;
#pragma unroll
            for (int j = 0; j < 4; j++) {
                int gm = m0 + mc + j;
                As[krow][mc + j] = (gm < M && gk < K) ? Ab[(size_t)gk * lda + gm] : 0.f;
            }
        }
        {
            int krow = tid >> 4;
            int nc = (tid & 15) * 4;
            int gk = k0 + krow;
#pragma unroll
            for (int j = 0; j < 4; j++) {
                int gn = n0 + nc + j;
                Bs[krow][nc + j] = (gk < K && gn < N) ? Bb[(size_t)gk * ldb + gn] : 0.f;
            }
        }
        __syncthreads();
#pragma unroll
        for (int k = 0; k < 16; k++) {
            float a[4], bv[4];
#pragma unroll
            for (int i = 0; i < 4; i++) a[i] = As[k][ty * 4 + i];
#pragma unroll
            for (int j = 0; j < 4; j++) bv[j] = Bs[k][tx * 4 + j];
#pragma unroll
            for (int i = 0; i < 4; i++)
#pragma unroll
                for (int j = 0; j < 4; j++) acc[i][j] += a[i] * bv[j];
        }
        __syncthreads();
    }

#pragma unroll
    for (int i = 0; i < 4; i++) {
        int gm = m0 + ty * 4 + i;
        if (gm >= M) continue;
#pragma unroll
        for (int j = 0; j < 4; j++) {
            int gn = n0 + tx * 4 + j;
            if (gn >= N) continue;
            float v = acc[i][j];
            if (bias) v += bias[gn];
            if (act == 1) v = silu_f(v);
            else if (act == 2) v = softplus_f(v);
            size_t ci = (size_t)gm * ldc + gn;
            if (accum) Cb[ci] += v;
            else Cb[ci] = v;
        }
    }
}

// ---------------------------------------------------------------------------
// Column softmax stats over s axis: one thread per (b, lat) column.
// ---------------------------------------------------------------------------
__global__ __launch_bounds__(256) void colstats_kernel(const float* __restrict__ w,
                                                       float* __restrict__ colst)
{
    int idx = blockIdx.x * 256 + threadIdx.x;  // 0 .. B*LAT-1
    int b = idx / LATC;
    int l = idx % LATC;
    const float* base = w + (size_t)b * SS * LATC + l;
    float m = -1e30f, s = 0.f;
    for (int t = 0; t < SS; t++) {
        float v = base[(size_t)t * LATC];
        float nm = fmaxf(m, v);
        s = s * __expf(m - nm) + __expf(v - nm);
        m = nm;
    }
    colst[idx * 2] = m;
    colst[idx * 2 + 1] = s;
}

// ---------------------------------------------------------------------------
// weights = 0.5*(row_softmax(w)*LAT/S + col_softmax(w)), in place.
// ---------------------------------------------------------------------------
__global__ __launch_bounds__(256) void softmix_kernel(float* __restrict__ w,
                                                      const float* __restrict__ colst)
{
    int bs = blockIdx.x;   // 0..B*S-1
    int b = bs / SS;
    int l = threadIdx.x;
    float* row = w + (size_t)bs * LATC;
    float v = row[l];

    __shared__ float sm[256];
    sm[l] = v;
    __syncthreads();
    for (int st = 128; st > 0; st >>= 1) {
        if (l < st) sm[l] = fmaxf(sm[l], sm[l + st]);
        __syncthreads();
    }
    float rmax = sm[0];
    __syncthreads();
    float e = __expf(v - rmax);
    sm[l] = e;
    __syncthreads();
    for (int st = 128; st > 0; st >>= 1) {
        if (l < st) sm[l] += sm[l + st];
        __syncthreads();
    }
    float rsum = sm[0];

    float w1 = e / rsum * ((float)LATC / (float)SS);
    float cm = colst[(b * LATC + l) * 2];
    float cs = colst[(b * LATC + l) * 2 + 1];
    float w2 = __expf(v - cm) / cs;
    row[l] = 0.5f * (w1 + w2);
}

// ---------------------------------------------------------------------------
// RMSNorm row kernel: out = x / max(||x||,1e-12) * 32 * gamma  (D=1024)
// ---------------------------------------------------------------------------
__global__ __launch_bounds__(256) void rmsnorm_kernel(const float* __restrict__ x,
                                                      const float* __restrict__ gamma,
                                                      float* __restrict__ out)
{
    int row = blockIdx.x;  // B*LAT
    const float* xr = x + (size_t)row * D_OUTC;
    float v[4];
    float ss = 0.f;
#pragma unroll
    for (int i = 0; i < 4; i++) {
        v[i] = xr[threadIdx.x + i * 256];
        ss += v[i] * v[i];
    }
#pragma unroll
    for (int off = 32; off >= 1; off >>= 1) ss += __shfl_xor(ss, off, 64);
    __shared__ float sred[4];
    int wave = threadIdx.x >> 6;
    if ((threadIdx.x & 63) == 0) sred[wave] = ss;
    __syncthreads();
    float tot = sred[0] + sred[1] + sred[2] + sred[3];
    float inv = 32.0f / fmaxf(sqrtf(tot), 1e-12f);
    float* outr = out + (size_t)row * D_OUTC;
#pragma unroll
    for (int i = 0; i < 4; i++) {
        int d = threadIdx.x + i * 256;
        outr[d] = v[i] * inv * gamma[d];
    }
}

// ---------------------------------------------------------------------------
// Causal depthwise conv (width 4) + bias + silu.
// ---------------------------------------------------------------------------
__global__ __launch_bounds__(256) void conv_silu_kernel(const float* __restrict__ xz,
                                                        const float* __restrict__ cw,
                                                        const float* __restrict__ cb,
                                                        float* __restrict__ xh, int L)
{
    int idx = blockIdx.x * 256 + threadIdx.x;  // B*L*DINNER
    int c = idx % DINNER;
    int bl = idx / DINNER;
    int l = bl % L;
    int b = bl / L;
    float acc = cb[c];
#pragma unroll
    for (int j = 0; j < DCONV; j++) {
        int ls = l - (DCONV - 1) + j;
        if (ls >= 0)
            acc += xz[((size_t)(b * L + ls)) * (2 * DINNER) + c] * cw[c * DCONV + j];
    }
    xh[idx] = silu_f(acc);
}

// ---------------------------------------------------------------------------
// Selective scan: one thread per (b, d). 32 states in registers.
// dty holds dt on entry; y written IN PLACE (thread (b,d) owns column (b,:,d),
// read-before-write within each l). Fuses +D*xh and *silu(z).
// ---------------------------------------------------------------------------
__global__ __launch_bounds__(256) void scan_kernel(float* dty,
                                                   const float* __restrict__ xh,
                                                   const float* __restrict__ xz,
                                                   const float* __restrict__ xdbc,
                                                   const float* __restrict__ A_log,
                                                   const float* __restrict__ Dp,
                                                   int L)
{
    int idx = blockIdx.x * 256 + threadIdx.x;  // B*DINNER
    int d = idx % DINNER;
    int b = idx / DINNER;

    float A[NSTATE], h[NSTATE];
#pragma unroll
    for (int n = 0; n < NSTATE; n++) {
        A[n] = -__expf(A_log[d * NSTATE + n]);
        h[n] = 0.f;
    }
    float Dd = Dp[d];

    for (int l = 0; l < L; l++) {
        size_t rbl = (size_t)(b * L + l);
        float dtv = dty[rbl * DINNER + d];
        float xv = xh[rbl * DINNER + d];
        float zv = xz[rbl * (2 * DINNER) + DINNER + d];
        const float* bc = xdbc + rbl * 128 + DTRANK;  // B at +0, C at +32
        float dtx = dtv * xv;
        float accv = 0.f;
#pragma unroll
        for (int n = 0; n < NSTATE; n++) {
            float dA = __expf(dtv * A[n]);
            h[n] = dA * h[n] + dtx * bc[n];
            accv += h[n] * bc[NSTATE + n];
        }
        float yv = accv + Dd * xv;
        yv *= silu_f(zv);
        dty[rbl * DINNER + d] = yv;
    }
}

// ---------------------------------------------------------------------------

extern "C" void kernel_launch(void* const* d_in, const int* in_sizes, int n_in,
                              void* d_out, int out_size, void* d_ws, size_t ws_size,
                              hipStream_t stream)
{
    // All inputs fp32 (R8: fp32 reads ran finite; bf16 reads would have been
    // half-extent => the earlier NaNs were garbage bf16 decodes of fp32 data).
    // Output fp32 (documented contract: reference output dtype float32 ->
    // float*; R6-round kernel wrote full fp32 extent to d_out without fault).
    const float* x      = (const float*)d_in[0];
    const float* W_in   = (const float*)d_in[1];
    const float* b_in   = (const float*)d_in[2];
    const float* Wa1    = (const float*)d_in[3];
    const float* ba1    = (const float*)d_in[4];
    const float* Wa2    = (const float*)d_in[5];
    const float* ba2    = (const float*)d_in[6];
    const float* gamma  = (const float*)d_in[7];
    const float* in_w   = (const float*)d_in[8];
    const float* conv_w = (const float*)d_in[9];
    const float* conv_b = (const float*)d_in[10];
    const float* x_w    = (const float*)d_in[11];
    const float* dt_w   = (const float*)d_in[12];
    const float* dt_b   = (const float*)d_in[13];
    const float* A_log  = (const float*)d_in[14];
    const float* Dp     = (const float*)d_in[15];
    const float* out_w  = (const float*)d_in[16];
    float* latout = (float*)d_out;  // [B, LAT, D_OUT] fp32; fully written step 6

    float* ws = (float*)d_ws;
    const size_t SZ_OUT0 = (size_t)BB * SS * D_OUTC;   // 16,777,216 floats
    const size_t SZ_BSLAT = (size_t)BB * SS * LATC;    //  4,194,304
    const size_t SZ_LATD = (size_t)BB * LATC * D_OUTC; //  2,097,152

    // Layout: out0[16.78M] | wbuf[4.19M] | t1[4.19M] | colst[4K] = 100.7 MB
    // (extent proven writable across R2/R6/R7/R8 runs).
    float* out0 = ws;
    float* wbuf = out0 + SZ_OUT0;
    float* t1 = wbuf + SZ_BSLAT;
    float* colst = t1 + SZ_BSLAT;

    // Phase-2 reuse (after step 6: out0/wbuf/t1 dead):
    //   xz|xh|dtbuf tile out0 exactly; unorm+xdbc strictly inside wbuf;
    //   scan output in place over dtbuf.
    float* xz = out0;                                  // [0 : 8,388,608)
    float* xh = out0 + (size_t)BB * LATC * 2 * DINNER; // [8,388,608 : 12,582,912)
    float* dtbuf = xh + (size_t)BB * LATC * DINNER;    // [12,582,912 : 16,777,216)
    float* unorm = wbuf;                               // wbuf[0 : 2,097,152)
    float* xdbc = wbuf + SZ_LATD;                      // wbuf[2,097,152 : 2,359,296)

    dim3 blk(16, 16);
    const int L = LATC;
    const int M1 = BB * SS;   // 16384
    const int ML = BB * L;    // 2048

    // 1) out0 = x @ W_in + b_in
    gemm_kernel<<<dim3(D_OUTC / 64, M1 / 64, 1), blk, 0, stream>>>(
        x, D_IN, 0, W_in, D_OUTC, 0, b_in, out0, D_OUTC, 0, M1, D_OUTC, D_IN, 0, 0, 0);

    // 2) t1 = silu(out0 @ Wa1 + ba1)
    gemm_kernel<<<dim3(LATC / 64, M1 / 64, 1), blk, 0, stream>>>(
        out0, D_OUTC, 0, Wa1, LATC, 0, ba1, t1, LATC, 0, M1, LATC, D_OUTC, 0, 1, 0);

    // 3) wbuf = t1 @ Wa2 + ba2
    gemm_kernel<<<dim3(LATC / 64, M1 / 64, 1), blk, 0, stream>>>(
        t1, LATC, 0, Wa2, LATC, 0, ba2, wbuf, LATC, 0, M1, LATC, LATC, 0, 0, 0);

    // 4) column stats + 5) mix softmaxes in place
    colstats_kernel<<<dim3(BB * LATC / 256), dim3(256), 0, stream>>>(wbuf, colst);
    softmix_kernel<<<dim3(BB * SS), dim3(256), 0, stream>>>(wbuf, colst);

    // 6) latout[b] = weights[b]^T @ out0[b]   (batched, transA) -> all of d_out
    gemm_kernel<<<dim3(D_OUTC / 64, LATC / 64, BB), blk, 0, stream>>>(
        wbuf, LATC, (long)SS * LATC, out0, D_OUTC, (long)SS * D_OUTC, (const float*)nullptr,
        latout, D_OUTC, (long)LATC * D_OUTC, LATC, D_OUTC, SS, 1, 0, 0);

    // 7) two mamba blocks
    for (int i = 0; i < 2; i++) {
        const float* in_wi = in_w + (size_t)i * D_OUTC * 2 * DINNER;
        const float* cwi = conv_w + (size_t)i * DINNER * DCONV;
        const float* cbi = conv_b + (size_t)i * DINNER;
        const float* xwi = x_w + (size_t)i * DINNER * (DTRANK + 2 * NSTATE);
        const float* dtwi = dt_w + (size_t)i * DTRANK * DINNER;
        const float* dtbi = dt_b + (size_t)i * DINNER;
        const float* Ali = A_log + (size_t)i * DINNER * NSTATE;
        const float* Dpi = Dp + (size_t)i * DINNER;
        const float* owi = out_w + (size_t)i * DINNER * D_OUTC;
        const float* gi = gamma + (size_t)i * D_OUTC;

        // a) RMSNorm
        rmsnorm_kernel<<<dim3(ML), dim3(256), 0, stream>>>(latout, gi, unorm);

        // b) xz = unorm @ in_proj_w[i]   [ML, 4096]
        gemm_kernel<<<dim3(2 * DINNER / 64, ML / 64, 1), blk, 0, stream>>>(
            unorm, D_OUTC, 0, in_wi, 2 * DINNER, 0, (const float*)nullptr,
            xz, 2 * DINNER, 0, ML, 2 * DINNER, D_OUTC, 0, 0, 0);

        // c) xh = silu(causal_conv(xz[:, :DINNER]) + cb)
        conv_silu_kernel<<<dim3(BB * L * DINNER / 256), dim3(256), 0, stream>>>(xz, cwi, cbi, xh, L);

        // d) xdbc = xh @ x_proj_w[i]   [ML, 128]
        gemm_kernel<<<dim3(2, ML / 64, 1), blk, 0, stream>>>(
            xh, DINNER, 0, xwi, 128, 0, (const float*)nullptr,
            xdbc, 128, 0, ML, 128, DINNER, 0, 0, 0);

        // e) dt = softplus(xdbc[:, :64] @ dt_proj_w[i] + dt_proj_b[i])   [ML, 2048]
        gemm_kernel<<<dim3(DINNER / 64, ML / 64, 1), blk, 0, stream>>>(
            xdbc, 128, 0, dtwi, DINNER, 0, dtbi, dtbuf, DINNER, 0, ML, DINNER, DTRANK, 0, 2, 0);

        // f) selective scan (+ D*xh, * silu(z)); y in place over dtbuf
        scan_kernel<<<dim3(BB * DINNER / 256), dim3(256), 0, stream>>>(
            dtbuf, xh, xz, xdbc, Ali, Dpi, L);

        // g) latout += y @ out_proj_w[i]
        gemm_kernel<<<dim3(D_OUTC / 64, ML / 64, 1), blk, 0, stream>>>(
            dtbuf, DINNER, 0, owi, D_OUTC, 0, (const float*)nullptr,
            latout, D_OUTC, 0, ML, D_OUTC, DINNER, 0, 0, 1);
    }
}

// Round 10
// 2431.190 us; speedup vs baseline: 1.8453x; 1.8453x over previous
//
#include <hip/hip_runtime.h>
#include <math.h>

#define BB 8
#define SS 2048
#define D_IN 1024
#define D_OUTC 1024
#define LATC 256
#define NSTATE 32
#define DINNER 2048
#define DCONV 4
#define DTRANK 64

__device__ __forceinline__ float silu_f(float v) { return v * (1.f / (1.f + __expf(-v))); }
__device__ __forceinline__ float softplus_f(float v) {
    return fmaxf(v, 0.f) + log1pf(__expf(-fabsf(v)));
}

typedef short short8 __attribute__((ext_vector_type(8)));
typedef float f32x4 __attribute__((ext_vector_type(4)));

__device__ __forceinline__ short f2bf(float f) {
    unsigned u = __builtin_bit_cast(unsigned, f);
    u += 0x7FFFu + ((u >> 16) & 1u);          // round-to-nearest-even
    return (short)(u >> 16);
}
__device__ __forceinline__ int pack2(float a, float b) {
    return (int)((unsigned)(unsigned short)f2bf(a) | ((unsigned)(unsigned short)f2bf(b) << 16));
}

// ---------------------------------------------------------------------------
// bf16 MFMA GEMM: C[M,N] = act(A @ B + bias) (optionally +=), fp32 I/O.
// A fp32 [M,K] (or [K,M] if transA), B fp32 [K,N]. Converted to bf16 in LDS.
// Tile 128x128, BK=32, 256 threads = 4 waves (2x2), each wave 64x64 via
// 4x4 mfma_f32_16x16x32_bf16. Requires M%128==0, N%128==0, K%32==0.
// LDS layout: As[m][k], Bs[n][k], padded stride 40 shorts (2-way max = free).
// ---------------------------------------------------------------------------
__global__ __launch_bounds__(256) void gemm_mfma(
    const float* __restrict__ A, int lda, long strideA,
    const float* __restrict__ B, int ldb, long strideB,
    const float* __restrict__ bias,
    float* __restrict__ C, int ldc, long strideC,
    int M, int N, int K, int transA, int act, int accum)
{
    __shared__ __align__(16) short As[128][40];
    __shared__ __align__(16) short Bs[128][40];

    const int bz = blockIdx.z;
    const float* Ab = A + (size_t)bz * strideA;
    const float* Bb = B + (size_t)bz * strideB;
    float* Cb = C + (size_t)bz * strideC;

    const int tid = threadIdx.x;
    const int lane = tid & 63;
    const int wave = tid >> 6;   // 0..3
    const int wr = wave >> 1;    // wave row 0..1
    const int wc = wave & 1;     // wave col 0..1
    const int quad = lane >> 4;  // 0..3
    const int l16 = lane & 15;

    const int m0 = blockIdx.y * 128;
    const int n0 = blockIdx.x * 128;

    f32x4 acc[4][4];
#pragma unroll
    for (int i = 0; i < 4; i++)
#pragma unroll
        for (int j = 0; j < 4; j++) acc[i][j] = (f32x4){0.f, 0.f, 0.f, 0.f};

    for (int k0 = 0; k0 < K; k0 += 32) {
        // ---- stage A ----
        if (!transA) {
            // A[m][k]: 128 rows x 32 floats; thread: row=tid>>1, 16-float half
            int row = tid >> 1;
            int c0 = (tid & 1) * 16;
            const float* src = Ab + (size_t)(m0 + row) * lda + (k0 + c0);
            float4 f0 = *(const float4*)(src);
            float4 f1 = *(const float4*)(src + 4);
            float4 f2 = *(const float4*)(src + 8);
            float4 f3 = *(const float4*)(src + 12);
            int4 w0, w1;
            w0.x = pack2(f0.x, f0.y); w0.y = pack2(f0.z, f0.w);
            w0.z = pack2(f1.x, f1.y); w0.w = pack2(f1.z, f1.w);
            w1.x = pack2(f2.x, f2.y); w1.y = pack2(f2.z, f2.w);
            w1.z = pack2(f3.x, f3.y); w1.w = pack2(f3.z, f3.w);
            *(int4*)&As[row][c0] = w0;
            *(int4*)&As[row][c0 + 8] = w1;
        } else {
            // A[k][m]: 32 rows x 128 cols -> As[m][k] (transpose into LDS)
            int kr = tid >> 3;
            int x0 = (tid & 7) * 16;
            const float* src = Ab + (size_t)(k0 + kr) * lda + (m0 + x0);
#pragma unroll
            for (int q = 0; q < 4; q++) {
                float4 f = *(const float4*)(src + q * 4);
                As[x0 + q * 4 + 0][kr] = f2bf(f.x);
                As[x0 + q * 4 + 1][kr] = f2bf(f.y);
                As[x0 + q * 4 + 2][kr] = f2bf(f.z);
                As[x0 + q * 4 + 3][kr] = f2bf(f.w);
            }
        }
        // ---- stage B: B[k][n]: 32 rows x 128 cols -> Bs[n][k] ----
        {
            int kr = tid >> 3;
            int x0 = (tid & 7) * 16;
            const float* src = Bb + (size_t)(k0 + kr) * ldb + (n0 + x0);
#pragma unroll
            for (int q = 0; q < 4; q++) {
                float4 f = *(const float4*)(src + q * 4);
                Bs[x0 + q * 4 + 0][kr] = f2bf(f.x);
                Bs[x0 + q * 4 + 1][kr] = f2bf(f.y);
                Bs[x0 + q * 4 + 2][kr] = f2bf(f.z);
                Bs[x0 + q * 4 + 3][kr] = f2bf(f.w);
            }
        }
        __syncthreads();

        short8 af[4], bfr[4];
#pragma unroll
        for (int i = 0; i < 4; i++) {
            af[i] = *(const short8*)&As[wr * 64 + i * 16 + l16][quad * 8];
            bfr[i] = *(const short8*)&Bs[wc * 64 + i * 16 + l16][quad * 8];
        }
#pragma unroll
        for (int i = 0; i < 4; i++)
#pragma unroll
            for (int j = 0; j < 4; j++)
                acc[i][j] = __builtin_amdgcn_mfma_f32_16x16x32_bf16(af[i], bfr[j], acc[i][j], 0, 0, 0);
        __syncthreads();
    }

    // epilogue: D mapping col = lane&15, row = quad*4 + reg
#pragma unroll
    for (int j = 0; j < 4; j++) {
        int gn = n0 + wc * 64 + j * 16 + l16;
        float bv = bias ? bias[gn] : 0.f;
#pragma unroll
        for (int i = 0; i < 4; i++) {
#pragma unroll
            for (int r = 0; r < 4; r++) {
                int gm = m0 + wr * 64 + i * 16 + quad * 4 + r;
                float v = acc[i][j][r] + bv;
                if (act == 1) v = silu_f(v);
                else if (act == 2) v = softplus_f(v);
                size_t ci = (size_t)gm * ldc + gn;
                if (accum) Cb[ci] += v;
                else Cb[ci] = v;
            }
        }
    }
}

// ---------------------------------------------------------------------------
// fp32 SIMT GEMM (kept for small / accuracy-sensitive GEMMs: x_proj, dt_proj)
// ---------------------------------------------------------------------------
__global__ __launch_bounds__(256) void gemm_kernel(
    const float* __restrict__ A, int lda, long strideA,
    const float* __restrict__ B, int ldb, long strideB,
    const float* __restrict__ bias,
    float* __restrict__ C, int ldc, long strideC,
    int M, int N, int K, int transA, int act, int accum)
{
    __shared__ float As[16][65];
    __shared__ float Bsh[16][64];

    const int bz = blockIdx.z;
    const float* Ab = A + (size_t)bz * strideA;
    const float* Bb = B + (size_t)bz * strideB;
    float* Cb = C + (size_t)bz * strideC;

    const int tx = threadIdx.x;
    const int ty = threadIdx.y;
    const int tid = ty * 16 + tx;
    const int m0 = blockIdx.y * 64;
    const int n0 = blockIdx.x * 64;

    float acc[4][4];
#pragma unroll
    for (int i = 0; i < 4; i++)
#pragma unroll
        for (int j = 0; j < 4; j++) acc[i][j] = 0.f;

    for (int k0 = 0; k0 < K; k0 += 16) {
        if (!transA) {
            int row = tid >> 2;
            int kc = (tid & 3) * 4;
            int gm = m0 + row;
#pragma unroll
            for (int j = 0; j < 4; j++) {
                int gk = k0 + kc + j;
                As[kc + j][row] = (gm < M && gk < K) ? Ab[(size_t)gm * lda + gk] : 0.f;
            }
        } else {
            int krow = tid >> 4;
            int mc = (tid & 15) * 4;
            int gk = k0 + krow;
#pragma unroll
            for (int j = 0; j < 4; j++) {
                int gm = m0 + mc + j;
                As[krow][mc + j] = (gm < M && gk < K) ? Ab[(size_t)gk * lda + gm] : 0.f;
            }
        }
        {
            int krow = tid >> 4;
            int nc = (tid & 15) * 4;
            int gk = k0 + krow;
#pragma unroll
            for (int j = 0; j < 4; j++) {
                int gn = n0 + nc + j;
                Bsh[krow][nc + j] = (gk < K && gn < N) ? Bb[(size_t)gk * ldb + gn] : 0.f;
            }
        }
        __syncthreads();
#pragma unroll
        for (int k = 0; k < 16; k++) {
            float a[4], bv[4];
#pragma unroll
            for (int i = 0; i < 4; i++) a[i] = As[k][ty * 4 + i];
#pragma unroll
            for (int j = 0; j < 4; j++) bv[j] = Bsh[k][tx * 4 + j];
#pragma unroll
            for (int i = 0; i < 4; i++)
#pragma unroll
                for (int j = 0; j < 4; j++) acc[i][j] += a[i] * bv[j];
        }
        __syncthreads();
    }

#pragma unroll
    for (int i = 0; i < 4; i++) {
        int gm = m0 + ty * 4 + i;
        if (gm >= M) continue;
#pragma unroll
        for (int j = 0; j < 4; j++) {
            int gn = n0 + tx * 4 + j;
            if (gn >= N) continue;
            float v = acc[i][j];
            if (bias) v += bias[gn];
            if (act == 1) v = silu_f(v);
            else if (act == 2) v = softplus_f(v);
            size_t ci = (size_t)gm * ldc + gn;
            if (accum) Cb[ci] += v;
            else Cb[ci] = v;
        }
    }
}

// ---------------------------------------------------------------------------
__global__ __launch_bounds__(256) void colstats_kernel(const float* __restrict__ w,
                                                       float* __restrict__ colst)
{
    int idx = blockIdx.x * 256 + threadIdx.x;
    int b = idx / LATC;
    int l = idx % LATC;
    const float* base = w + (size_t)b * SS * LATC + l;
    float m = -1e30f, s = 0.f;
    for (int t = 0; t < SS; t++) {
        float v = base[(size_t)t * LATC];
        float nm = fmaxf(m, v);
        s = s * __expf(m - nm) + __expf(v - nm);
        m = nm;
    }
    colst[idx * 2] = m;
    colst[idx * 2 + 1] = s;
}

__global__ __launch_bounds__(256) void softmix_kernel(float* __restrict__ w,
                                                      const float* __restrict__ colst)
{
    int bs = blockIdx.x;
    int b = bs / SS;
    int l = threadIdx.x;
    float* row = w + (size_t)bs * LATC;
    float v = row[l];

    __shared__ float sm[256];
    sm[l] = v;
    __syncthreads();
    for (int st = 128; st > 0; st >>= 1) {
        if (l < st) sm[l] = fmaxf(sm[l], sm[l + st]);
        __syncthreads();
    }
    float rmax = sm[0];
    __syncthreads();
    float e = __expf(v - rmax);
    sm[l] = e;
    __syncthreads();
    for (int st = 128; st > 0; st >>= 1) {
        if (l < st) sm[l] += sm[l + st];
        __syncthreads();
    }
    float rsum = sm[0];

    float w1 = e / rsum * ((float)LATC / (float)SS);
    float cm = colst[(b * LATC + l) * 2];
    float cs = colst[(b * LATC + l) * 2 + 1];
    float w2 = __expf(v - cm) / cs;
    row[l] = 0.5f * (w1 + w2);
}

__global__ __launch_bounds__(256) void rmsnorm_kernel(const float* __restrict__ x,
                                                      const float* __restrict__ gamma,
                                                      float* __restrict__ out)
{
    int row = blockIdx.x;
    const float* xr = x + (size_t)row * D_OUTC;
    float v[4];
    float ss = 0.f;
#pragma unroll
    for (int i = 0; i < 4; i++) {
        v[i] = xr[threadIdx.x + i * 256];
        ss += v[i] * v[i];
    }
#pragma unroll
    for (int off = 32; off >= 1; off >>= 1) ss += __shfl_xor(ss, off, 64);
    __shared__ float sred[4];
    int wave = threadIdx.x >> 6;
    if ((threadIdx.x & 63) == 0) sred[wave] = ss;
    __syncthreads();
    float tot = sred[0] + sred[1] + sred[2] + sred[3];
    float inv = 32.0f / fmaxf(sqrtf(tot), 1e-12f);
    float* outr = out + (size_t)row * D_OUTC;
#pragma unroll
    for (int i = 0; i < 4; i++) {
        int d = threadIdx.x + i * 256;
        outr[d] = v[i] * inv * gamma[d];
    }
}

__global__ __launch_bounds__(256) void conv_silu_kernel(const float* __restrict__ xz,
                                                        const float* __restrict__ cw,
                                                        const float* __restrict__ cb,
                                                        float* __restrict__ xh, int L)
{
    int idx = blockIdx.x * 256 + threadIdx.x;
    int c = idx % DINNER;
    int bl = idx / DINNER;
    int l = bl % L;
    int b = bl / L;
    float acc = cb[c];
#pragma unroll
    for (int j = 0; j < DCONV; j++) {
        int ls = l - (DCONV - 1) + j;
        if (ls >= 0)
            acc += xz[((size_t)(b * L + ls)) * (2 * DINNER) + c] * cw[c * DCONV + j];
    }
    xh[idx] = silu_f(acc);
}

__global__ __launch_bounds__(256) void scan_kernel(float* dty,
                                                   const float* __restrict__ xh,
                                                   const float* __restrict__ xz,
                                                   const float* __restrict__ xdbc,
                                                   const float* __restrict__ A_log,
                                                   const float* __restrict__ Dp,
                                                   int L)
{
    int idx = blockIdx.x * 256 + threadIdx.x;
    int d = idx % DINNER;
    int b = idx / DINNER;

    float A[NSTATE], h[NSTATE];
#pragma unroll
    for (int n = 0; n < NSTATE; n++) {
        A[n] = -__expf(A_log[d * NSTATE + n]);
        h[n] = 0.f;
    }
    float Dd = Dp[d];

    for (int l = 0; l < L; l++) {
        size_t rbl = (size_t)(b * L + l);
        float dtv = dty[rbl * DINNER + d];
        float xv = xh[rbl * DINNER + d];
        float zv = xz[rbl * (2 * DINNER) + DINNER + d];
        const float* bc = xdbc + rbl * 128 + DTRANK;
        float dtx = dtv * xv;
        float accv = 0.f;
#pragma unroll
        for (int n = 0; n < NSTATE; n++) {
            float dA = __expf(dtv * A[n]);
            h[n] = dA * h[n] + dtx * bc[n];
            accv += h[n] * bc[NSTATE + n];
        }
        float yv = accv + Dd * xv;
        yv *= silu_f(zv);
        dty[rbl * DINNER + d] = yv;
    }
}

// ---------------------------------------------------------------------------

extern "C" void kernel_launch(void* const* d_in, const int* in_sizes, int n_in,
                              void* d_out, int out_size, void* d_ws, size_t ws_size,
                              hipStream_t stream)
{
    const float* x      = (const float*)d_in[0];
    const float* W_in   = (const float*)d_in[1];
    const float* b_in   = (const float*)d_in[2];
    const float* Wa1    = (const float*)d_in[3];
    const float* ba1    = (const float*)d_in[4];
    const float* Wa2    = (const float*)d_in[5];
    const float* ba2    = (const float*)d_in[6];
    const float* gamma  = (const float*)d_in[7];
    const float* in_w   = (const float*)d_in[8];
    const float* conv_w = (const float*)d_in[9];
    const float* conv_b = (const float*)d_in[10];
    const float* x_w    = (const float*)d_in[11];
    const float* dt_w   = (const float*)d_in[12];
    const float* dt_b   = (const float*)d_in[13];
    const float* A_log  = (const float*)d_in[14];
    const float* Dp     = (const float*)d_in[15];
    const float* out_w  = (const float*)d_in[16];
    float* latout = (float*)d_out;

    float* ws = (float*)d_ws;
    const size_t SZ_OUT0 = (size_t)BB * SS * D_OUTC;
    const size_t SZ_BSLAT = (size_t)BB * SS * LATC;
    const size_t SZ_LATD = (size_t)BB * LATC * D_OUTC;

    float* out0 = ws;
    float* wbuf = out0 + SZ_OUT0;
    float* t1 = wbuf + SZ_BSLAT;
    float* colst = t1 + SZ_BSLAT;

    float* xz = out0;
    float* xh = out0 + (size_t)BB * LATC * 2 * DINNER;
    float* dtbuf = xh + (size_t)BB * LATC * DINNER;
    float* unorm = wbuf;
    float* xdbc = wbuf + SZ_LATD;

    dim3 blk(16, 16);
    const int L = LATC;
    const int M1 = BB * SS;   // 16384
    const int ML = BB * L;    // 2048

    // 1) out0 = x @ W_in + b_in   [16384,1024,1024]  (MFMA)
    gemm_mfma<<<dim3(D_OUTC / 128, M1 / 128, 1), dim3(256), 0, stream>>>(
        x, D_IN, 0, W_in, D_OUTC, 0, b_in, out0, D_OUTC, 0, M1, D_OUTC, D_IN, 0, 0, 0);

    // 2) t1 = silu(out0 @ Wa1 + ba1)   [16384,256,1024]  (MFMA)
    gemm_mfma<<<dim3(LATC / 128, M1 / 128, 1), dim3(256), 0, stream>>>(
        out0, D_OUTC, 0, Wa1, LATC, 0, ba1, t1, LATC, 0, M1, LATC, D_OUTC, 0, 1, 0);

    // 3) wbuf = t1 @ Wa2 + ba2   [16384,256,256]  (MFMA)
    gemm_mfma<<<dim3(LATC / 128, M1 / 128, 1), dim3(256), 0, stream>>>(
        t1, LATC, 0, Wa2, LATC, 0, ba2, wbuf, LATC, 0, M1, LATC, LATC, 0, 0, 0);

    // 4/5) softmax mix
    colstats_kernel<<<dim3(BB * LATC / 256), dim3(256), 0, stream>>>(wbuf, colst);
    softmix_kernel<<<dim3(BB * SS), dim3(256), 0, stream>>>(wbuf, colst);

    // 6) latout[b] = weights[b]^T @ out0[b]   [256,1024,2048]x8  (MFMA, transA)
    gemm_mfma<<<dim3(D_OUTC / 128, LATC / 128, BB), dim3(256), 0, stream>>>(
        wbuf, LATC, (long)SS * LATC, out0, D_OUTC, (long)SS * D_OUTC, (const float*)nullptr,
        latout, D_OUTC, (long)LATC * D_OUTC, LATC, D_OUTC, SS, 1, 0, 0);

    // 7) two mamba blocks
    for (int i = 0; i < 2; i++) {
        const float* in_wi = in_w + (size_t)i * D_OUTC * 2 * DINNER;
        const float* cwi = conv_w + (size_t)i * DINNER * DCONV;
        const float* cbi = conv_b + (size_t)i * DINNER;
        const float* xwi = x_w + (size_t)i * DINNER * (DTRANK + 2 * NSTATE);
        const float* dtwi = dt_w + (size_t)i * DTRANK * DINNER;
        const float* dtbi = dt_b + (size_t)i * DINNER;
        const float* Ali = A_log + (size_t)i * DINNER * NSTATE;
        const float* Dpi = Dp + (size_t)i * DINNER;
        const float* owi = out_w + (size_t)i * DINNER * D_OUTC;
        const float* gi = gamma + (size_t)i * D_OUTC;

        // a) RMSNorm
        rmsnorm_kernel<<<dim3(ML), dim3(256), 0, stream>>>(latout, gi, unorm);

        // b) xz = unorm @ in_proj_w[i]   [2048,4096,1024]  (MFMA)
        gemm_mfma<<<dim3(2 * DINNER / 128, ML / 128, 1), dim3(256), 0, stream>>>(
            unorm, D_OUTC, 0, in_wi, 2 * DINNER, 0, (const float*)nullptr,
            xz, 2 * DINNER, 0, ML, 2 * DINNER, D_OUTC, 0, 0, 0);

        // c) xh = silu(causal_conv(xz[:, :DINNER]) + cb)
        conv_silu_kernel<<<dim3(BB * L * DINNER / 256), dim3(256), 0, stream>>>(xz, cwi, cbi, xh, L);

        // d) xdbc = xh @ x_proj_w[i]   [2048,128,2048]  (fp32 — dt-chain accuracy)
        gemm_kernel<<<dim3(2, ML / 64, 1), blk, 0, stream>>>(
            xh, DINNER, 0, xwi, 128, 0, (const float*)nullptr,
            xdbc, 128, 0, ML, 128, DINNER, 0, 0, 0);

        // e) dt = softplus(xdbc[:, :64] @ dt_proj_w[i] + dt_b[i])  [2048,2048,64]  (fp32)
        gemm_kernel<<<dim3(DINNER / 64, ML / 64, 1), blk, 0, stream>>>(
            xdbc, 128, 0, dtwi, DINNER, 0, dtbi, dtbuf, DINNER, 0, ML, DINNER, DTRANK, 0, 2, 0);

        // f) selective scan; y in place over dtbuf
        scan_kernel<<<dim3(BB * DINNER / 256), dim3(256), 0, stream>>>(
            dtbuf, xh, xz, xdbc, Ali, Dpi, L);

        // g) latout += y @ out_proj_w[i]   [2048,1024,2048]  (MFMA, accum)
        gemm_mfma<<<dim3(D_OUTC / 128, ML / 128, 1), dim3(256), 0, stream>>>(
            dtbuf, DINNER, 0, owi, D_OUTC, 0, (const float*)nullptr,
            latout, D_OUTC, 0, ML, D_OUTC, DINNER, 0, 0, 1);
    }
}